// Round 12
// baseline (136.421 us; speedup 1.0000x reference)
//
#include <hip/hip_runtime.h>

#define BATCH 4
#define TLEN 8192
#define NLAYER 20
#define NTILE 128          // TLEN/64 real tiles
#define GUARD 8            // zero guard tiles (max dil 512 = 8*64)
#define ATILE (NTILE + GUARD)
#define CELL 4096          // 8 cg * 64 n * 8 j elements per (b,tile)

typedef __attribute__((ext_vector_type(8))) short bf16x8;
typedef __attribute__((ext_vector_type(8))) unsigned short u16x8;
typedef __attribute__((ext_vector_type(4))) short s16x4;
typedef __attribute__((ext_vector_type(4))) float f32x4;

__device__ __forceinline__ unsigned short f2b(float f) {
    unsigned u = __float_as_uint(f);
    return (unsigned short)((u + 0x7fffu + ((u >> 16) & 1u)) >> 16);  // RNE
}
__device__ __forceinline__ unsigned cvtpk(float lo, float hi) {
    unsigned r;
    asm("v_cvt_pk_bf16_f32 %0, %1, %2" : "=v"(r) : "v"(lo), "v"(hi));
    return r;
}

// ---------------- prep: weights -> fragment-ordered bf16 ----------------
// w1f[l][ks7][slot8][lane64][j8]; slot = wv*2 + half. half0 -> tanh row 16wv+(lane&15),
// half1 -> sigmoid row 64+16wv+(lane&15)  (pairs land in one lane's acc[0]/acc[1]).
// w2f[l][ks2][slot4][..]  res rows; wsf[l][ks2][slot8][..] skip rows.
__global__ void prep_w(const float* __restrict__ conv_w, const float* __restrict__ conv_b,
                       const float* __restrict__ cond_w, const float* __restrict__ cond_b,
                       const float* __restrict__ res_w,  const float* __restrict__ res_b,
                       const float* __restrict__ skip_w, const float* __restrict__ skip_b,
                       unsigned short* __restrict__ w1f, unsigned short* __restrict__ w2f,
                       unsigned short* __restrict__ wsf,
                       float* __restrict__ hb, float* __restrict__ rb, float* __restrict__ sbt) {
    const int l = blockIdx.x, tid = threadIdx.x;
    const int start = blockIdx.y * 256 + tid;
    for (int idx = start; idx < 7 * 8 * 512; idx += 2048) {
        int ks = idx >> 12;
        int slot = (idx >> 9) & 7, lane = (idx >> 3) & 63, j = idx & 7;
        int m = (slot & 1) * 64 + (slot >> 1) * 16 + (lane & 15);   // interleaved pairing
        int k = ks * 32 + ((lane >> 4) << 3) + j;
        float v;
        if (k < 64)       v = conv_w[(((size_t)l * 128 + m) * 64 + k) * 2 + 0];
        else if (k < 128) v = conv_w[(((size_t)l * 128 + m) * 64 + (k - 64)) * 2 + 1];
        else if (k < 208) v = cond_w[((size_t)l * 128 + m) * 80 + (k - 128)];
        else              v = 0.0f;
        w1f[(size_t)l * 7 * 8 * 512 + idx] = f2b(v);
    }
    for (int idx = start; idx < 2 * 4 * 512; idx += 2048) {
        int ks = idx >> 11;
        int slot = (idx >> 9) & 3, lane = (idx >> 3) & 63, j = idx & 7;
        int m = slot * 16 + (lane & 15);
        int k = ks * 32 + ((lane >> 4) << 3) + j;
        w2f[(size_t)l * 2 * 4 * 512 + idx] = f2b(res_w[((size_t)l * 64 + m) * 64 + k]);
    }
    for (int idx = start; idx < 2 * 8 * 512; idx += 2048) {
        int ks = idx >> 12;
        int slot = (idx >> 9) & 7, lane = (idx >> 3) & 63, j = idx & 7;
        int m = slot * 16 + (lane & 15);
        int k = ks * 32 + ((lane >> 4) << 3) + j;
        wsf[(size_t)l * 2 * 8 * 512 + idx] = f2b(skip_w[((size_t)l * 128 + m) * 64 + k]);
    }
    if (blockIdx.y == 0) {
        if (tid < 128) hb[l * 128 + tid] = conv_b[l * 128 + tid] + cond_b[l * 128 + tid];
        if (tid < 64)  rb[l * 64 + tid] = res_b[l * 64 + tid];
        if (l == 0 && tid < 128) {
            float s = 0.f;
            for (int q = 0; q < NLAYER; ++q) s += skip_b[q * 128 + tid];
            sbt[tid] = s;
        }
    }
}

// ---------------- prep: x -> bf16 cells slot0, cond -> bf16 cells; zero guards+flags ----------------
__global__ void prep_xc(const float* __restrict__ x, const float* __restrict__ cond,
                        unsigned short* __restrict__ xall, unsigned short* __restrict__ condc,
                        unsigned* __restrict__ flags) {
    const int tile = blockIdx.x, b = blockIdx.y, tid = threadIdx.x;
    if (tile < GUARD) {
        s16x4 zh = {0, 0, 0, 0};
        for (int s = 0; s < NLAYER; ++s) {
            unsigned short* g = xall + ((size_t)s * BATCH + b) * ATILE * CELL + (size_t)tile * CELL;
            for (int idx = tid * 4; idx < CELL; idx += 1024)
                *(s16x4*)(g + idx) = zh;
        }
        if (tile == 0)
            for (int i = tid; i < NTILE * 32; i += 256)
                flags[(size_t)b * NTILE * 32 + i] = 0u;
        return;
    }
    __shared__ float xt[64][64];
    __shared__ float ct[80][64];
    const int rt = tile - GUARD;
    for (int idx = tid; idx < 64 * 64; idx += 256) {
        int ch = idx >> 6, n = idx & 63;
        xt[ch][n] = x[((size_t)b * 64 + ch) * TLEN + rt * 64 + n];
    }
    for (int idx = tid; idx < 80 * 64; idx += 256) {
        int ch = idx >> 6, n = idx & 63;
        ct[ch][n] = cond[((size_t)b * 80 + ch) * TLEN + rt * 64 + n];
    }
    __syncthreads();
    unsigned short* s0 = xall + ((size_t)b * ATILE + tile) * CELL;   // slot 0
    for (int idx = tid; idx < 8 * 64; idx += 256) {
        int cg = idx >> 6, n = idx & 63;
        unsigned short* dbf = s0 + ((size_t)cg * 64 + n) * 8;
        #pragma unroll
        for (int j = 0; j < 8; ++j) dbf[j] = f2b(xt[cg * 8 + j][n]);
    }
    for (int idx = tid; idx < 12 * 64; idx += 256) {
        int cg = idx >> 6, n = idx & 63;
        u16x8 cell;
        #pragma unroll
        for (int j = 0; j < 8; ++j) {
            int ch = cg * 8 + j;
            cell[j] = (ch < 80) ? f2b(ct[ch][n]) : (unsigned short)0;
        }
        *(u16x8*)(condc + (((size_t)(b * NTILE + rt) * 12 + cg) * 64 + n) * 8) = cell;
    }
}

// ---------------- fused persistent kernel: all 20 layers (R11 base + XCD swizzle) ----------------
// tile = (bid%8)*16 + bid/8 : HW assigns XCD = flattened_bid % 8 (grid.x=128 divisible
// by 8, so y doesn't shift it). Consecutive tiles share an XCD chunk -> the per-layer
// publish/tap exchange stays on-die for kd=1/2/4 (94%) and half of kd=8.
__global__ __launch_bounds__(256, 2) void wavenet_fused(
    const float* __restrict__ x, const unsigned short* __restrict__ condc,
    unsigned short* __restrict__ xall,
    const unsigned short* __restrict__ w1f, const unsigned short* __restrict__ w2f,
    const unsigned short* __restrict__ wsf,
    const float* __restrict__ hb, const float* __restrict__ rb,
    const float* __restrict__ sbt, float* __restrict__ out,
    unsigned* __restrict__ flags) {
    __shared__ unsigned short s_cond[12 * 512];   // 12 KB
    __shared__ unsigned short s_xc[CELL];         //  8 KB own-tile x bf16 cells
    __shared__ unsigned short s_zc[CELL];         //  8 KB z bf16 cells

    const int b = blockIdx.y;
    const int bid = blockIdx.x;
    const int tile = (bid & 7) * 16 + (bid >> 3);   // XCD-chunked mapping (bijective)
    const int t0 = tile * 64;
    const int tid = threadIdx.x, lane = tid & 63;
    const int wv = __builtin_amdgcn_readfirstlane(tid >> 6);
    const int ln = lane & 15, lg = lane >> 4;
    const int r0 = wv * 16 + lg * 4;              // this lane's 4 rows (z / res)
    const int cgz = r0 >> 3, j0z = r0 & 7;        // cell coords for those rows
    const size_t bslot = (size_t)BATCH * ATILE * CELL;

    // stage cond + initial x cells into LDS
    {
        const u16x8* cc = (const u16x8*)(condc + (size_t)(b * NTILE + tile) * 12 * 512);
        u16x8* sc = (u16x8*)s_cond;
        for (int i = tid; i < 768; i += 256) sc[i] = cc[i];
        const u16x8* xc = (const u16x8*)(xall + ((size_t)b * ATILE + tile + GUARD) * CELL);
        u16x8* sx = (u16x8*)s_xc;
        for (int i = tid; i < 512; i += 256) sx[i] = xc[i];
    }

    // xs fp32 residual state in registers
    f32x4 xsr[4];
    #pragma unroll
    for (int nf = 0; nf < 4; ++nf)
        #pragma unroll
        for (int r = 0; r < 4; ++r)
            xsr[nf][r] = x[((size_t)b * 64 + r0 + r) * TLEN + t0 + nf * 16 + ln];

    // skip accumulator in registers
    f32x4 skacc[2][4];
    #pragma unroll
    for (int mf = 0; mf < 2; ++mf)
        #pragma unroll
        for (int nf = 0; nf < 4; ++nf) skacc[mf][nf] = (f32x4){0.f, 0.f, 0.f, 0.f};

    // cached neighbor progress per tap distance (named regs, no dyn indexing)
    unsigned fc1 = 0, fc2 = 0, fc4 = 0, fc8 = 0;
    unsigned* myflag = flags + ((size_t)b * NTILE + tile) * 32 + wv;

    __syncthreads();

    for (int l = 0; l < NLAYER; ++l) {
        const int dil = 1 << ((l < 10) ? l : (l - 10));

        // ---- top barrier (LDS reuse ordering) + per-wave cached flag poll ----
        if (l > 0) {
            __syncthreads();
            const int kd = (dil + 63) >> 6;
            const int tp = tile - kd;
            if (tp >= 0) {
                unsigned cached = (kd == 1) ? fc1 : (kd == 2) ? fc2 : (kd == 4) ? fc4 : fc8;
                if (cached < (unsigned)l) {
                    const unsigned* fp = flags + ((size_t)b * NTILE + tp) * 32 + (lane & 3);
                    unsigned v;
                    for (;;) {
                        v = __hip_atomic_load(fp, __ATOMIC_RELAXED, __HIP_MEMORY_SCOPE_AGENT);
                        unsigned v1 = (unsigned)__shfl_xor((int)v, 1);
                        v = (v1 < v) ? v1 : v;
                        unsigned v2 = (unsigned)__shfl_xor((int)v, 2);
                        v = (v2 < v) ? v2 : v;          // wave-uniform min of 4 flags
                        if (v >= (unsigned)l) break;
                        __builtin_amdgcn_s_sleep(1);
                    }
                    if (kd == 1) fc1 = v; else if (kd == 2) fc2 = v;
                    else if (kd == 4) fc4 = v; else fc8 = v;
                }
            }
            // keep the remote loads below from being hoisted above the spin
            __builtin_amdgcn_sched_barrier(0);
        }

        const unsigned short* xrb = xall + (size_t)l * bslot + (size_t)b * ATILE * CELL;
        const unsigned short* w1l = w1f + (size_t)l * 7 * 8 * 512;

        // ---- issue remote tap loads + remote A-frag weights FIRST ----
        bf16x8 brem[2][4];
        #pragma unroll
        for (int ks = 0; ks < 2; ++ks) {
            const int cg = ks * 4 + lg;
            #pragma unroll
            for (int nf = 0; nf < 4; ++nf) {
                int u = t0 + nf * 16 + ln - dil + GUARD * 64;   // >= 0 always
                brem[ks][nf] = *(const bf16x8*)(xrb + (((size_t)(u >> 6) * 8 + cg) * 64 + (u & 63)) * 8);
            }
        }
        bf16x8 raf[4];
        raf[0] = *(const bf16x8*)(w1l + (size_t)(0 * 8 + wv * 2 + 0) * 512 + lane * 8);
        raf[1] = *(const bf16x8*)(w1l + (size_t)(0 * 8 + wv * 2 + 1) * 512 + lane * 8);
        raf[2] = *(const bf16x8*)(w1l + (size_t)(1 * 8 + wv * 2 + 0) * 512 + lane * 8);
        raf[3] = *(const bf16x8*)(w1l + (size_t)(1 * 8 + wv * 2 + 1) * 512 + lane * 8);

        // ---- local GEMM1 chain (ks2..6): 40 MFMA while remote loads fly ----
        f32x4 acc[2][4];
        #pragma unroll
        for (int hf = 0; hf < 2; ++hf)
            #pragma unroll
            for (int nf = 0; nf < 4; ++nf) acc[hf][nf] = (f32x4){0.f, 0.f, 0.f, 0.f};

        #pragma unroll
        for (int ks = 2; ks < 7; ++ks) {
            bf16x8 af0 = *(const bf16x8*)(w1l + (size_t)(ks * 8 + wv * 2 + 0) * 512 + lane * 8);
            bf16x8 af1 = *(const bf16x8*)(w1l + (size_t)(ks * 8 + wv * 2 + 1) * 512 + lane * 8);
            bf16x8 bfr[4];
            if (ks < 4) {                 // current tap: own tile from LDS
                const int cg = (ks - 2) * 4 + lg;
                #pragma unroll
                for (int nf = 0; nf < 4; ++nf)
                    bfr[nf] = *(const bf16x8*)(s_xc + ((cg * 64) + nf * 16 + ln) * 8);
            } else {                      // cond from LDS
                const int cg = (ks - 4) * 4 + lg;
                #pragma unroll
                for (int nf = 0; nf < 4; ++nf)
                    bfr[nf] = *(const bf16x8*)(s_cond + ((cg * 64) + nf * 16 + ln) * 8);
            }
            #pragma unroll
            for (int nf = 0; nf < 4; ++nf) {
                acc[0][nf] = __builtin_amdgcn_mfma_f32_16x16x32_bf16(af0, bfr[nf], acc[0][nf], 0, 0, 0);
                acc[1][nf] = __builtin_amdgcn_mfma_f32_16x16x32_bf16(af1, bfr[nf], acc[1][nf], 0, 0, 0);
            }
        }

        // ---- remote MFMAs last (ks0,1) ----
        #pragma unroll
        for (int ks = 0; ks < 2; ++ks) {
            #pragma unroll
            for (int nf = 0; nf < 4; ++nf) {
                acc[0][nf] = __builtin_amdgcn_mfma_f32_16x16x32_bf16(raf[ks * 2 + 0], brem[ks][nf], acc[0][nf], 0, 0, 0);
                acc[1][nf] = __builtin_amdgcn_mfma_f32_16x16x32_bf16(raf[ks * 2 + 1], brem[ks][nf], acc[1][nf], 0, 0, 0);
            }
        }

        // ---- gate fully in-register -> z cells to LDS ----
        {
            const float* hbl = hb + l * 128;
            float4 hbt = *(const float4*)(hbl + r0);
            float4 hbs = *(const float4*)(hbl + 64 + r0);
            #pragma unroll
            for (int nf = 0; nf < 4; ++nf) {
                float zr[4];
                #pragma unroll
                for (int r = 0; r < 4; ++r) {
                    float a  = acc[0][nf][r] + ((r == 0) ? hbt.x : (r == 1) ? hbt.y : (r == 2) ? hbt.z : hbt.w);
                    float bs = acc[1][nf][r] + ((r == 0) ? hbs.x : (r == 1) ? hbs.y : (r == 2) ? hbs.z : hbs.w);
                    float e = __expf(a + a);
                    float s = __expf(-bs);
                    zr[r] = __fdividef(e - 1.0f, (e + 1.0f) * (1.0f + s));
                }
                union { unsigned u32[2]; s16x4 v; } pk;
                pk.u32[0] = cvtpk(zr[0], zr[1]);
                pk.u32[1] = cvtpk(zr[2], zr[3]);
                *(s16x4*)(&s_zc[((cgz * 64) + nf * 16 + ln) * 8 + j0z]) = pk.v;
            }
        }
        __syncthreads();   // BARRIER A: z visible to all waves

        // ---- z fragments + skip-weight PRELOAD (before publish stores!) ----
        bf16x8 bz[2][4];
        #pragma unroll
        for (int ks = 0; ks < 2; ++ks)
            #pragma unroll
            for (int nf = 0; nf < 4; ++nf)
                bz[ks][nf] = *(const bf16x8*)(&s_zc[(((ks * 4 + lg) * 64) + nf * 16 + ln) * 8]);
        const unsigned short* wsl = wsf + (size_t)l * 2 * 8 * 512;
        bf16x8 sw[2][2];
        #pragma unroll
        for (int ks = 0; ks < 2; ++ks) {
            sw[ks][0] = *(const bf16x8*)(wsl + (size_t)(ks * 8 + wv * 2 + 0) * 512 + lane * 8);
            sw[ks][1] = *(const bf16x8*)(wsl + (size_t)(ks * 8 + wv * 2 + 1) * 512 + lane * 8);
        }

        // ---- res GEMM (critical path) ----
        f32x4 acc2[4];
        #pragma unroll
        for (int nf = 0; nf < 4; ++nf) acc2[nf] = (f32x4){0.f, 0.f, 0.f, 0.f};
        const unsigned short* w2l = w2f + (size_t)l * 2 * 4 * 512;
        #pragma unroll
        for (int ks = 0; ks < 2; ++ks) {
            bf16x8 a2 = *(const bf16x8*)(w2l + (size_t)(ks * 4 + wv) * 512 + lane * 8);
            #pragma unroll
            for (int nf = 0; nf < 4; ++nf)
                acc2[nf] = __builtin_amdgcn_mfma_f32_16x16x32_bf16(a2, bz[ks][nf], acc2[nf], 0, 0, 0);
        }

        // ---- epilogue: residual add in registers; issue publish stores ----
        {
            const float* rbl = rb + l * 64;
            float4 rbv = *(const float4*)(rbl + r0);
            unsigned short* xwt = xall + (size_t)(l + 1) * bslot +
                                  ((size_t)b * ATILE + tile + GUARD) * CELL;
            #pragma unroll
            for (int nf = 0; nf < 4; ++nf) {
                xsr[nf][0] += acc2[nf][0] + rbv.x;
                xsr[nf][1] += acc2[nf][1] + rbv.y;
                xsr[nf][2] += acc2[nf][2] + rbv.z;
                xsr[nf][3] += acc2[nf][3] + rbv.w;
                if (l < NLAYER - 1) {
                    int n = nf * 16 + ln;
                    union { unsigned u32[2]; s16x4 v; unsigned long long u64; } pk;
                    pk.u32[0] = cvtpk(xsr[nf][0], xsr[nf][1]);
                    pk.u32[1] = cvtpk(xsr[nf][2], xsr[nf][3]);
                    *(s16x4*)(&s_xc[(cgz * 64 + n) * 8 + j0z]) = pk.v;
                    // agent-scope write-through: coherent at LLC, no wbl2 needed
                    __hip_atomic_store((unsigned long long*)(xwt + ((size_t)cgz * 64 + n) * 8 + j0z),
                                       pk.u64, __ATOMIC_RELAXED, __HIP_MEMORY_SCOPE_AGENT);
                }
            }
        }

        // ---- skip GEMM (weights preloaded; hides part of the store drain) ----
        #pragma unroll
        for (int ks = 0; ks < 2; ++ks)
            #pragma unroll
            for (int nf = 0; nf < 4; ++nf) {
                skacc[0][nf] = __builtin_amdgcn_mfma_f32_16x16x32_bf16(sw[ks][0], bz[ks][nf], skacc[0][nf], 0, 0, 0);
                skacc[1][nf] = __builtin_amdgcn_mfma_f32_16x16x32_bf16(sw[ks][1], bz[ks][nf], skacc[1][nf], 0, 0, 0);
            }

        // ---- per-wave: drain my publish stores, post my flag ----
        if (l < NLAYER - 1) {
            asm volatile("s_waitcnt vmcnt(0)" ::: "memory");
            if (lane == 0)
                __hip_atomic_store(myflag, (unsigned)(l + 1),
                                   __ATOMIC_RELAXED, __HIP_MEMORY_SCOPE_AGENT);
        }
    }

    // ---- final: skip_total + summed skip bias -> out ----
    #pragma unroll
    for (int mf = 0; mf < 2; ++mf)
        #pragma unroll
        for (int nf = 0; nf < 4; ++nf)
            #pragma unroll
            for (int r = 0; r < 4; ++r) {
                int m = wv * 32 + mf * 16 + lg * 4 + r;
                out[((size_t)b * 128 + m) * TLEN + t0 + nf * 16 + ln] =
                    skacc[mf][nf][r] + sbt[m];
            }
}

extern "C" void kernel_launch(void* const* d_in, const int* in_sizes, int n_in,
                              void* d_out, int out_size, void* d_ws, size_t ws_size,
                              hipStream_t stream) {
    const float* x      = (const float*)d_in[0];
    const float* cond   = (const float*)d_in[1];
    const float* conv_w = (const float*)d_in[2];
    const float* conv_b = (const float*)d_in[3];
    const float* cond_w = (const float*)d_in[4];
    const float* cond_b = (const float*)d_in[5];
    const float* res_w  = (const float*)d_in[6];
    const float* res_b  = (const float*)d_in[7];
    const float* skip_w = (const float*)d_in[8];
    const float* skip_b = (const float*)d_in[9];
    float* out = (float*)d_out;

    char* ws = (char*)d_ws;
    const size_t XALL  = (size_t)NLAYER * BATCH * ATILE * CELL * 2;  // 89,128,960
    const size_t COND  = (size_t)BATCH * NTILE * 12 * 512 * 2;       //  6,291,456
    const size_t W1    = (size_t)NLAYER * 7 * 8 * 512 * 2;           //  1,146,880
    const size_t W2    = (size_t)NLAYER * 2 * 4 * 512 * 2;           //    163,840
    const size_t WSF   = (size_t)NLAYER * 2 * 8 * 512 * 2;           //    327,680
    const size_t HB    = NLAYER * 128 * 4;
    const size_t RB    = NLAYER * 64 * 4;
    const size_t SBT   = 256 * 4;
    const size_t FLAGS = (size_t)BATCH * NTILE * 32 * 4;             //     65,536

    size_t off = 0;
    unsigned short* xall  = (unsigned short*)(ws + off); off += XALL;
    unsigned short* condc = (unsigned short*)(ws + off); off += COND;
    unsigned short* w1f   = (unsigned short*)(ws + off); off += W1;
    unsigned short* w2f   = (unsigned short*)(ws + off); off += W2;
    unsigned short* wsf   = (unsigned short*)(ws + off); off += WSF;
    float* hb  = (float*)(ws + off); off += HB;
    float* rb  = (float*)(ws + off); off += RB;
    float* sbt = (float*)(ws + off); off += SBT;
    unsigned* flags = (unsigned*)(ws + off); off += FLAGS;

    prep_w<<<dim3(NLAYER, 8), 256, 0, stream>>>(conv_w, conv_b, cond_w, cond_b,
                                                res_w, res_b, skip_w, skip_b,
                                                w1f, w2f, wsf, hb, rb, sbt);
    prep_xc<<<dim3(ATILE, BATCH), 256, 0, stream>>>(x, cond, xall, condc, flags);

    wavenet_fused<<<dim3(NTILE, BATCH), 256, 0, stream>>>(
        x, condc, xall, w1f, w2f, wsf, hb, rb, sbt, out, flags);
}

// Round 13
// 118.110 us; speedup vs baseline: 1.1550x; 1.1550x over previous
//
#include <hip/hip_runtime.h>

#define BATCH 4
#define TLEN 8192
#define NLAYER 20
#define NTILE 128          // TLEN/64 real tiles
#define GUARD 8            // zero guard tiles (max dil 512 = 8*64)
#define ATILE (NTILE + GUARD)
#define CELL 4096          // 8 cg * 64 n * 8 j elements per (b,tile)

typedef __attribute__((ext_vector_type(8))) short bf16x8;
typedef __attribute__((ext_vector_type(8))) unsigned short u16x8;
typedef __attribute__((ext_vector_type(4))) short s16x4;
typedef __attribute__((ext_vector_type(4))) float f32x4;

__device__ __forceinline__ unsigned short f2b(float f) {
    unsigned u = __float_as_uint(f);
    return (unsigned short)((u + 0x7fffu + ((u >> 16) & 1u)) >> 16);  // RNE
}
__device__ __forceinline__ unsigned cvtpk(float lo, float hi) {
    unsigned r;
    asm("v_cvt_pk_bf16_f32 %0, %1, %2" : "=v"(r) : "v"(lo), "v"(hi));
    return r;
}

// ---------------- fused prep: weights + x/cond cells in ONE launch ----------------
// blocks [0, NLAYER*8): weight repack (l = bid>>3, part = bid&7)
// blocks [NLAYER*8, +ATILE*BATCH): x/cond cell prep (tile-major)
// w1f[l][ks7][slot8][lane64][j8]; slot = wv*2 + half; half0 -> tanh row 16wv+(lane&15),
// half1 -> sigmoid row 64+16wv+(lane&15). w2f res rows; wsf skip rows.
__global__ void prep_all(const float* __restrict__ x, const float* __restrict__ cond,
                         const float* __restrict__ conv_w, const float* __restrict__ conv_b,
                         const float* __restrict__ cond_w, const float* __restrict__ cond_b,
                         const float* __restrict__ res_w,  const float* __restrict__ res_b,
                         const float* __restrict__ skip_w, const float* __restrict__ skip_b,
                         unsigned short* __restrict__ w1f, unsigned short* __restrict__ w2f,
                         unsigned short* __restrict__ wsf, float* __restrict__ hb,
                         float* __restrict__ rb, float* __restrict__ sbt,
                         unsigned short* __restrict__ xall, unsigned short* __restrict__ condc,
                         unsigned* __restrict__ flags) {
    __shared__ float xt[64][64];
    __shared__ float ct[80][64];
    const int bid = blockIdx.x, tid = threadIdx.x;

    if (bid < NLAYER * 8) {
        const int l = bid >> 3;
        const int start = (bid & 7) * 256 + tid;
        for (int idx = start; idx < 7 * 8 * 512; idx += 2048) {
            int ks = idx >> 12;
            int slot = (idx >> 9) & 7, lane = (idx >> 3) & 63, j = idx & 7;
            int m = (slot & 1) * 64 + (slot >> 1) * 16 + (lane & 15);   // pair interleave
            int k = ks * 32 + ((lane >> 4) << 3) + j;
            float v;
            if (k < 64)       v = conv_w[(((size_t)l * 128 + m) * 64 + k) * 2 + 0];
            else if (k < 128) v = conv_w[(((size_t)l * 128 + m) * 64 + (k - 64)) * 2 + 1];
            else if (k < 208) v = cond_w[((size_t)l * 128 + m) * 80 + (k - 128)];
            else              v = 0.0f;
            w1f[(size_t)l * 7 * 8 * 512 + idx] = f2b(v);
        }
        for (int idx = start; idx < 2 * 4 * 512; idx += 2048) {
            int ks = idx >> 11;
            int slot = (idx >> 9) & 3, lane = (idx >> 3) & 63, j = idx & 7;
            int m = slot * 16 + (lane & 15);
            int k = ks * 32 + ((lane >> 4) << 3) + j;
            w2f[(size_t)l * 2 * 4 * 512 + idx] = f2b(res_w[((size_t)l * 64 + m) * 64 + k]);
        }
        for (int idx = start; idx < 2 * 8 * 512; idx += 2048) {
            int ks = idx >> 12;
            int slot = (idx >> 9) & 7, lane = (idx >> 3) & 63, j = idx & 7;
            int m = slot * 16 + (lane & 15);
            int k = ks * 32 + ((lane >> 4) << 3) + j;
            wsf[(size_t)l * 2 * 8 * 512 + idx] = f2b(skip_w[((size_t)l * 128 + m) * 64 + k]);
        }
        if ((bid & 7) == 0) {
            if (tid < 128) hb[l * 128 + tid] = conv_b[l * 128 + tid] + cond_b[l * 128 + tid];
            if (tid < 64)  rb[l * 64 + tid] = res_b[l * 64 + tid];
            if (l == 0 && tid < 128) {
                float s = 0.f;
                for (int q = 0; q < NLAYER; ++q) s += skip_b[q * 128 + tid];
                sbt[tid] = s;
            }
        }
        return;
    }

    const int r = bid - NLAYER * 8;
    const int tile = r % ATILE, b = r / ATILE;
    if (tile < GUARD) {
        s16x4 zh = {0, 0, 0, 0};
        for (int s = 0; s < NLAYER; ++s) {
            unsigned short* g = xall + ((size_t)s * BATCH + b) * ATILE * CELL + (size_t)tile * CELL;
            for (int idx = tid * 4; idx < CELL; idx += 1024)
                *(s16x4*)(g + idx) = zh;
        }
        if (tile == 0)
            for (int i = tid; i < NTILE * 32; i += 256)
                flags[(size_t)b * NTILE * 32 + i] = 0u;
        return;
    }
    const int rt = tile - GUARD;
    for (int idx = tid; idx < 64 * 64; idx += 256) {
        int ch = idx >> 6, n = idx & 63;
        xt[ch][n] = x[((size_t)b * 64 + ch) * TLEN + rt * 64 + n];
    }
    for (int idx = tid; idx < 80 * 64; idx += 256) {
        int ch = idx >> 6, n = idx & 63;
        ct[ch][n] = cond[((size_t)b * 80 + ch) * TLEN + rt * 64 + n];
    }
    __syncthreads();
    unsigned short* s0 = xall + ((size_t)b * ATILE + tile) * CELL;   // slot 0
    for (int idx = tid; idx < 8 * 64; idx += 256) {
        int cg = idx >> 6, n = idx & 63;
        unsigned short* dbf = s0 + ((size_t)cg * 64 + n) * 8;
        #pragma unroll
        for (int j = 0; j < 8; ++j) dbf[j] = f2b(xt[cg * 8 + j][n]);
    }
    for (int idx = tid; idx < 12 * 64; idx += 256) {
        int cg = idx >> 6, n = idx & 63;
        u16x8 cell;
        #pragma unroll
        for (int j = 0; j < 8; ++j) {
            int ch = cg * 8 + j;
            cell[j] = (ch < 80) ? f2b(ct[ch][n]) : (unsigned short)0;
        }
        *(u16x8*)(condc + (((size_t)(b * NTILE + rt) * 12 + cg) * 64 + n) * 8) = cell;
    }
}

// ---------------- fused persistent kernel: all 20 layers (R11 base + cond hoist) ----------------
// Per layer l: acc already holds the cond (ks4..6) contribution, computed in the shadow
// after posting flag l-1. [top barrier] poll -> remote tap loads + A-frags -> own-tile
// MFMAs (ks2,3, covers LLC latency) -> remote MFMAs -> gate -> s_zc; BARRIER A; bz +
// skip-weight preload; res GEMM; publish; skip GEMM; drain; post; cond-MFMAs for l+1.
__global__ __launch_bounds__(256, 2) void wavenet_fused(
    const float* __restrict__ x, const unsigned short* __restrict__ condc,
    unsigned short* __restrict__ xall,
    const unsigned short* __restrict__ w1f, const unsigned short* __restrict__ w2f,
    const unsigned short* __restrict__ wsf,
    const float* __restrict__ hb, const float* __restrict__ rb,
    const float* __restrict__ sbt, float* __restrict__ out,
    unsigned* __restrict__ flags) {
    __shared__ unsigned short s_cond[12 * 512];   // 12 KB (layer-invariant)
    __shared__ unsigned short s_xc[CELL];         //  8 KB own-tile x bf16 cells
    __shared__ unsigned short s_zc[CELL];         //  8 KB z bf16 cells

    const int b = blockIdx.y, tile = blockIdx.x, t0 = tile * 64;
    const int tid = threadIdx.x, lane = tid & 63;
    const int wv = __builtin_amdgcn_readfirstlane(tid >> 6);
    const int ln = lane & 15, lg = lane >> 4;
    const int r0 = wv * 16 + lg * 4;              // this lane's 4 rows (z / res)
    const int cgz = r0 >> 3, j0z = r0 & 7;        // cell coords for those rows
    const size_t bslot = (size_t)BATCH * ATILE * CELL;

    // stage cond + initial x cells into LDS
    {
        const u16x8* cc = (const u16x8*)(condc + (size_t)(b * NTILE + tile) * 12 * 512);
        u16x8* sc = (u16x8*)s_cond;
        for (int i = tid; i < 768; i += 256) sc[i] = cc[i];
        const u16x8* xc = (const u16x8*)(xall + ((size_t)b * ATILE + tile + GUARD) * CELL);
        u16x8* sx = (u16x8*)s_xc;
        for (int i = tid; i < 512; i += 256) sx[i] = xc[i];
    }

    // xs fp32 residual state in registers
    f32x4 xsr[4];
    #pragma unroll
    for (int nf = 0; nf < 4; ++nf)
        #pragma unroll
        for (int r = 0; r < 4; ++r)
            xsr[nf][r] = x[((size_t)b * 64 + r0 + r) * TLEN + t0 + nf * 16 + ln];

    // skip accumulator in registers
    f32x4 skacc[2][4];
    #pragma unroll
    for (int mf = 0; mf < 2; ++mf)
        #pragma unroll
        for (int nf = 0; nf < 4; ++nf) skacc[mf][nf] = (f32x4){0.f, 0.f, 0.f, 0.f};

    // cached neighbor progress per tap distance (named regs, no dyn indexing)
    unsigned fc1 = 0, fc2 = 0, fc4 = 0, fc8 = 0;
    unsigned* myflag = flags + ((size_t)b * NTILE + tile) * 32 + wv;

    __syncthreads();

    // GEMM1 accumulators, carried across the loop: hold cond part for the next layer
    f32x4 acc[2][4];

    // precompute cond contribution (ks4..6) for layer 0
    {
        const unsigned short* w10 = w1f;
        #pragma unroll
        for (int hf = 0; hf < 2; ++hf)
            #pragma unroll
            for (int nf = 0; nf < 4; ++nf) acc[hf][nf] = (f32x4){0.f, 0.f, 0.f, 0.f};
        #pragma unroll
        for (int ks = 4; ks < 7; ++ks) {
            bf16x8 af0 = *(const bf16x8*)(w10 + (size_t)(ks * 8 + wv * 2 + 0) * 512 + lane * 8);
            bf16x8 af1 = *(const bf16x8*)(w10 + (size_t)(ks * 8 + wv * 2 + 1) * 512 + lane * 8);
            const int cg = (ks - 4) * 4 + lg;
            #pragma unroll
            for (int nf = 0; nf < 4; ++nf) {
                bf16x8 bfr = *(const bf16x8*)(s_cond + ((cg * 64) + nf * 16 + ln) * 8);
                acc[0][nf] = __builtin_amdgcn_mfma_f32_16x16x32_bf16(af0, bfr, acc[0][nf], 0, 0, 0);
                acc[1][nf] = __builtin_amdgcn_mfma_f32_16x16x32_bf16(af1, bfr, acc[1][nf], 0, 0, 0);
            }
        }
    }

    for (int l = 0; l < NLAYER; ++l) {
        const int dil = 1 << ((l < 10) ? l : (l - 10));

        // ---- top barrier (LDS reuse ordering) + per-wave cached flag poll ----
        if (l > 0) {
            __syncthreads();
            const int kd = (dil + 63) >> 6;
            const int tp = tile - kd;
            if (tp >= 0) {
                unsigned cached = (kd == 1) ? fc1 : (kd == 2) ? fc2 : (kd == 4) ? fc4 : fc8;
                if (cached < (unsigned)l) {
                    const unsigned* fp = flags + ((size_t)b * NTILE + tp) * 32 + (lane & 3);
                    unsigned v;
                    for (;;) {
                        v = __hip_atomic_load(fp, __ATOMIC_RELAXED, __HIP_MEMORY_SCOPE_AGENT);
                        unsigned v1 = (unsigned)__shfl_xor((int)v, 1);
                        v = (v1 < v) ? v1 : v;
                        unsigned v2 = (unsigned)__shfl_xor((int)v, 2);
                        v = (v2 < v) ? v2 : v;          // wave-uniform min of 4 flags
                        if (v >= (unsigned)l) break;
                        __builtin_amdgcn_s_sleep(2);
                    }
                    if (kd == 1) fc1 = v; else if (kd == 2) fc2 = v;
                    else if (kd == 4) fc4 = v; else fc8 = v;
                }
            }
            // keep the remote loads below from being hoisted above the spin
            __builtin_amdgcn_sched_barrier(0);
        }

        const unsigned short* xrb = xall + (size_t)l * bslot + (size_t)b * ATILE * CELL;
        const unsigned short* w1l = w1f + (size_t)l * 7 * 8 * 512;

        // ---- issue remote tap loads + remote A-frag weights FIRST ----
        bf16x8 brem[2][4];
        #pragma unroll
        for (int ks = 0; ks < 2; ++ks) {
            const int cg = ks * 4 + lg;
            #pragma unroll
            for (int nf = 0; nf < 4; ++nf) {
                int u = t0 + nf * 16 + ln - dil + GUARD * 64;   // >= 0 always
                brem[ks][nf] = *(const bf16x8*)(xrb + (((size_t)(u >> 6) * 8 + cg) * 64 + (u & 63)) * 8);
            }
        }
        bf16x8 raf[4];
        raf[0] = *(const bf16x8*)(w1l + (size_t)(0 * 8 + wv * 2 + 0) * 512 + lane * 8);
        raf[1] = *(const bf16x8*)(w1l + (size_t)(0 * 8 + wv * 2 + 1) * 512 + lane * 8);
        raf[2] = *(const bf16x8*)(w1l + (size_t)(1 * 8 + wv * 2 + 0) * 512 + lane * 8);
        raf[3] = *(const bf16x8*)(w1l + (size_t)(1 * 8 + wv * 2 + 1) * 512 + lane * 8);

        // ---- own-tile MFMAs (ks2,3): 16 MFMA while remote loads fly ----
        #pragma unroll
        for (int ks = 2; ks < 4; ++ks) {
            bf16x8 af0 = *(const bf16x8*)(w1l + (size_t)(ks * 8 + wv * 2 + 0) * 512 + lane * 8);
            bf16x8 af1 = *(const bf16x8*)(w1l + (size_t)(ks * 8 + wv * 2 + 1) * 512 + lane * 8);
            const int cg = (ks - 2) * 4 + lg;
            #pragma unroll
            for (int nf = 0; nf < 4; ++nf) {
                bf16x8 bfr = *(const bf16x8*)(s_xc + ((cg * 64) + nf * 16 + ln) * 8);
                acc[0][nf] = __builtin_amdgcn_mfma_f32_16x16x32_bf16(af0, bfr, acc[0][nf], 0, 0, 0);
                acc[1][nf] = __builtin_amdgcn_mfma_f32_16x16x32_bf16(af1, bfr, acc[1][nf], 0, 0, 0);
            }
        }

        // ---- remote MFMAs last (ks0,1) ----
        #pragma unroll
        for (int ks = 0; ks < 2; ++ks) {
            #pragma unroll
            for (int nf = 0; nf < 4; ++nf) {
                acc[0][nf] = __builtin_amdgcn_mfma_f32_16x16x32_bf16(raf[ks * 2 + 0], brem[ks][nf], acc[0][nf], 0, 0, 0);
                acc[1][nf] = __builtin_amdgcn_mfma_f32_16x16x32_bf16(raf[ks * 2 + 1], brem[ks][nf], acc[1][nf], 0, 0, 0);
            }
        }

        // ---- gate fully in-register -> z cells to LDS ----
        {
            const float* hbl = hb + l * 128;
            float4 hbt = *(const float4*)(hbl + r0);
            float4 hbs = *(const float4*)(hbl + 64 + r0);
            #pragma unroll
            for (int nf = 0; nf < 4; ++nf) {
                float zr[4];
                #pragma unroll
                for (int r = 0; r < 4; ++r) {
                    float a  = acc[0][nf][r] + ((r == 0) ? hbt.x : (r == 1) ? hbt.y : (r == 2) ? hbt.z : hbt.w);
                    float bs = acc[1][nf][r] + ((r == 0) ? hbs.x : (r == 1) ? hbs.y : (r == 2) ? hbs.z : hbs.w);
                    float e = __expf(a + a);
                    float s = __expf(-bs);
                    zr[r] = __fdividef(e - 1.0f, (e + 1.0f) * (1.0f + s));
                }
                union { unsigned u32[2]; s16x4 v; } pk;
                pk.u32[0] = cvtpk(zr[0], zr[1]);
                pk.u32[1] = cvtpk(zr[2], zr[3]);
                *(s16x4*)(&s_zc[((cgz * 64) + nf * 16 + ln) * 8 + j0z]) = pk.v;
            }
        }
        __syncthreads();   // BARRIER A: z visible to all waves

        // ---- z fragments + skip-weight PRELOAD (before publish stores!) ----
        bf16x8 bz[2][4];
        #pragma unroll
        for (int ks = 0; ks < 2; ++ks)
            #pragma unroll
            for (int nf = 0; nf < 4; ++nf)
                bz[ks][nf] = *(const bf16x8*)(&s_zc[(((ks * 4 + lg) * 64) + nf * 16 + ln) * 8]);
        const unsigned short* wsl = wsf + (size_t)l * 2 * 8 * 512;
        bf16x8 sw[2][2];
        #pragma unroll
        for (int ks = 0; ks < 2; ++ks) {
            sw[ks][0] = *(const bf16x8*)(wsl + (size_t)(ks * 8 + wv * 2 + 0) * 512 + lane * 8);
            sw[ks][1] = *(const bf16x8*)(wsl + (size_t)(ks * 8 + wv * 2 + 1) * 512 + lane * 8);
        }

        // ---- res GEMM (critical path) ----
        f32x4 acc2[4];
        #pragma unroll
        for (int nf = 0; nf < 4; ++nf) acc2[nf] = (f32x4){0.f, 0.f, 0.f, 0.f};
        const unsigned short* w2l = w2f + (size_t)l * 2 * 4 * 512;
        #pragma unroll
        for (int ks = 0; ks < 2; ++ks) {
            bf16x8 a2 = *(const bf16x8*)(w2l + (size_t)(ks * 4 + wv) * 512 + lane * 8);
            #pragma unroll
            for (int nf = 0; nf < 4; ++nf)
                acc2[nf] = __builtin_amdgcn_mfma_f32_16x16x32_bf16(a2, bz[ks][nf], acc2[nf], 0, 0, 0);
        }

        // ---- epilogue: residual add in registers; issue publish stores ----
        {
            const float* rbl = rb + l * 64;
            float4 rbv = *(const float4*)(rbl + r0);
            unsigned short* xwt = xall + (size_t)(l + 1) * bslot +
                                  ((size_t)b * ATILE + tile + GUARD) * CELL;
            #pragma unroll
            for (int nf = 0; nf < 4; ++nf) {
                xsr[nf][0] += acc2[nf][0] + rbv.x;
                xsr[nf][1] += acc2[nf][1] + rbv.y;
                xsr[nf][2] += acc2[nf][2] + rbv.z;
                xsr[nf][3] += acc2[nf][3] + rbv.w;
                if (l < NLAYER - 1) {
                    int n = nf * 16 + ln;
                    union { unsigned u32[2]; s16x4 v; unsigned long long u64; } pk;
                    pk.u32[0] = cvtpk(xsr[nf][0], xsr[nf][1]);
                    pk.u32[1] = cvtpk(xsr[nf][2], xsr[nf][3]);
                    *(s16x4*)(&s_xc[(cgz * 64 + n) * 8 + j0z]) = pk.v;
                    // agent-scope write-through: coherent at LLC, no wbl2 needed
                    __hip_atomic_store((unsigned long long*)(xwt + ((size_t)cgz * 64 + n) * 8 + j0z),
                                       pk.u64, __ATOMIC_RELAXED, __HIP_MEMORY_SCOPE_AGENT);
                }
            }
        }

        // ---- skip GEMM (weights preloaded; hides part of the store drain) ----
        #pragma unroll
        for (int ks = 0; ks < 2; ++ks)
            #pragma unroll
            for (int nf = 0; nf < 4; ++nf) {
                skacc[0][nf] = __builtin_amdgcn_mfma_f32_16x16x32_bf16(sw[ks][0], bz[ks][nf], skacc[0][nf], 0, 0, 0);
                skacc[1][nf] = __builtin_amdgcn_mfma_f32_16x16x32_bf16(sw[ks][1], bz[ks][nf], skacc[1][nf], 0, 0, 0);
            }

        // ---- per-wave: drain my publish stores, post my flag ----
        if (l < NLAYER - 1) {
            asm volatile("s_waitcnt vmcnt(0)" ::: "memory");
            if (lane == 0)
                __hip_atomic_store(myflag, (unsigned)(l + 1),
                                   __ATOMIC_RELAXED, __HIP_MEMORY_SCOPE_AGENT);
        }

        // ---- shadow work: cond MFMAs (ks4..6) for layer l+1 into acc ----
        if (l < NLAYER - 1) {
            const unsigned short* w1n = w1f + (size_t)(l + 1) * 7 * 8 * 512;
            #pragma unroll
            for (int hf = 0; hf < 2; ++hf)
                #pragma unroll
                for (int nf = 0; nf < 4; ++nf) acc[hf][nf] = (f32x4){0.f, 0.f, 0.f, 0.f};
            #pragma unroll
            for (int ks = 4; ks < 7; ++ks) {
                bf16x8 af0 = *(const bf16x8*)(w1n + (size_t)(ks * 8 + wv * 2 + 0) * 512 + lane * 8);
                bf16x8 af1 = *(const bf16x8*)(w1n + (size_t)(ks * 8 + wv * 2 + 1) * 512 + lane * 8);
                const int cg = (ks - 4) * 4 + lg;
                #pragma unroll
                for (int nf = 0; nf < 4; ++nf) {
                    bf16x8 bfr = *(const bf16x8*)(s_cond + ((cg * 64) + nf * 16 + ln) * 8);
                    acc[0][nf] = __builtin_amdgcn_mfma_f32_16x16x32_bf16(af0, bfr, acc[0][nf], 0, 0, 0);
                    acc[1][nf] = __builtin_amdgcn_mfma_f32_16x16x32_bf16(af1, bfr, acc[1][nf], 0, 0, 0);
                }
            }
        }
    }

    // ---- final: skip_total + summed skip bias -> out ----
    #pragma unroll
    for (int mf = 0; mf < 2; ++mf)
        #pragma unroll
        for (int nf = 0; nf < 4; ++nf)
            #pragma unroll
            for (int r = 0; r < 4; ++r) {
                int m = wv * 32 + mf * 16 + lg * 4 + r;
                out[((size_t)b * 128 + m) * TLEN + t0 + nf * 16 + ln] =
                    skacc[mf][nf][r] + sbt[m];
            }
}

extern "C" void kernel_launch(void* const* d_in, const int* in_sizes, int n_in,
                              void* d_out, int out_size, void* d_ws, size_t ws_size,
                              hipStream_t stream) {
    const float* x      = (const float*)d_in[0];
    const float* cond   = (const float*)d_in[1];
    const float* conv_w = (const float*)d_in[2];
    const float* conv_b = (const float*)d_in[3];
    const float* cond_w = (const float*)d_in[4];
    const float* cond_b = (const float*)d_in[5];
    const float* res_w  = (const float*)d_in[6];
    const float* res_b  = (const float*)d_in[7];
    const float* skip_w = (const float*)d_in[8];
    const float* skip_b = (const float*)d_in[9];
    float* out = (float*)d_out;

    char* ws = (char*)d_ws;
    const size_t XALL  = (size_t)NLAYER * BATCH * ATILE * CELL * 2;  // 89,128,960
    const size_t COND  = (size_t)BATCH * NTILE * 12 * 512 * 2;       //  6,291,456
    const size_t W1    = (size_t)NLAYER * 7 * 8 * 512 * 2;           //  1,146,880
    const size_t W2    = (size_t)NLAYER * 2 * 4 * 512 * 2;           //    163,840
    const size_t WSF   = (size_t)NLAYER * 2 * 8 * 512 * 2;           //    327,680
    const size_t HB    = NLAYER * 128 * 4;
    const size_t RB    = NLAYER * 64 * 4;
    const size_t SBT   = 256 * 4;
    const size_t FLAGS = (size_t)BATCH * NTILE * 32 * 4;             //     65,536

    size_t off = 0;
    unsigned short* xall  = (unsigned short*)(ws + off); off += XALL;
    unsigned short* condc = (unsigned short*)(ws + off); off += COND;
    unsigned short* w1f   = (unsigned short*)(ws + off); off += W1;
    unsigned short* w2f   = (unsigned short*)(ws + off); off += W2;
    unsigned short* wsf   = (unsigned short*)(ws + off); off += WSF;
    float* hb  = (float*)(ws + off); off += HB;
    float* rb  = (float*)(ws + off); off += RB;
    float* sbt = (float*)(ws + off); off += SBT;
    unsigned* flags = (unsigned*)(ws + off); off += FLAGS;

    prep_all<<<NLAYER * 8 + ATILE * BATCH, 256, 0, stream>>>(
        x, cond, conv_w, conv_b, cond_w, cond_b, res_w, res_b, skip_w, skip_b,
        w1f, w2f, wsf, hb, rb, sbt, xall, condc, flags);

    wavenet_fused<<<dim3(NTILE, BATCH), 256, 0, stream>>>(
        x, condc, xall, w1f, w2f, wsf, hb, rb, sbt, out, flags);
}